// Round 16
// baseline (105.185 us; speedup 1.0000x reference)
//
#include <hip/hip_runtime.h>

#define BATCH 2
#define SEQ   2048
#define DIN   1024
#define NH    16
#define DE    64
#define NT_KV (SEQ / 64)
#define HALF_KV (NT_KV / 2)
#define NROW  (BATCH * NH * SEQ)

typedef __attribute__((ext_vector_type(8))) short short8;
typedef __attribute__((ext_vector_type(4))) float f32x4;
typedef __attribute__((ext_vector_type(4))) unsigned short ushort4_t;
typedef __attribute__((ext_vector_type(8))) _Float16 f16x8;

static __device__ __forceinline__ f32x4 mfmaF(short8 a, short8 b, f32x4 c) {
    return __builtin_amdgcn_mfma_f32_16x16x32_f16(
        __builtin_bit_cast(f16x8, a), __builtin_bit_cast(f16x8, b), c, 0, 0, 0);
}
// async global->LDS, 16B per lane; dest = wave-uniform base + lane*16
static __device__ __forceinline__ void gld16(unsigned short* l, const unsigned short* g) {
    __builtin_amdgcn_global_load_lds(
        (const __attribute__((address_space(1))) void*)g,
        (__attribute__((address_space(3))) void*)l, 16, 0, 0);
}
static __device__ __forceinline__ int pkf16(float a, float b) {
    return __builtin_bit_cast(int, __builtin_amdgcn_cvt_pkrtz(a, b));
}
static __device__ __forceinline__ unsigned short f2h(float f) {
    return __builtin_bit_cast(unsigned short, (_Float16)f);   // RNE
}
static __device__ __forceinline__ float h2f(unsigned short u) {
    return (float)__builtin_bit_cast(_Float16, u);
}
// raw v_exp_f32 (args are always <= 8 here; negative underflow -> 0 is wanted)
static __device__ __forceinline__ float fexp2(float x) {
    return __builtin_amdgcn_exp2f(x);
}
// counted waits (T4): keep prefetch in flight across barriers
static __device__ __forceinline__ void wait_vm2()  { asm volatile("s_waitcnt vmcnt(2)" ::: "memory"); }
static __device__ __forceinline__ void wait_vm4()  { asm volatile("s_waitcnt vmcnt(4)" ::: "memory"); }
// swizzled b128 read from a [R][32] f16 tile (row-pair scheme), proj only
static __device__ __forceinline__ short8 lds32(const unsigned short* buf, int row, int g) {
    int p = row >> 1, e = ((row & 1) << 2) | g;
    return *reinterpret_cast<const short8*>(buf + p * 64 + ((e ^ (p & 7)) << 3));
}

// ---------------------------------------------------------------------------
// Kernel A: convert x (fp32) -> fp16. 2048 blocks x 256, 8 elem/thr.
// ---------------------------------------------------------------------------
__global__ __launch_bounds__(256)
void xcvt_kernel(const float* __restrict__ x, unsigned short* __restrict__ xo)
{
    size_t i0 = ((size_t)blockIdx.x * 256 + threadIdx.x) * 8;
    float4 a = *reinterpret_cast<const float4*>(&x[i0]);
    float4 b = *reinterpret_cast<const float4*>(&x[i0 + 4]);
    float vv[8] = {a.x, a.y, a.z, a.w, b.x, b.y, b.z, b.w};
    short8 sh;
    #pragma unroll
    for (int j = 0; j < 8; ++j) sh[j] = (short)f2h(vv[j]);
    *reinterpret_cast<short8*>(&xo[i0]) = sh;
}

// ---------------------------------------------------------------------------
// Kernel B: W transpose + fp16 convert. Wt rows: n = z*1024 + h*64 + e.
// ---------------------------------------------------------------------------
__global__ __launch_bounds__(256)
void wcvt_kernel(const float* __restrict__ Wq, const float* __restrict__ Wk,
                 const float* __restrict__ Wv, unsigned short* __restrict__ Wt)
{
    const int dt = blockIdx.x, h = blockIdx.y, z = blockIdx.z;
    const float* __restrict__ W = (z == 0) ? Wq : (z == 1) ? Wk : Wv;
    __shared__ float Ws[64][65];
    const int t = threadIdx.x;
    const int d0 = dt * 64;
    #pragma unroll
    for (int u = 0; u < 4; ++u) {
        int id = t + 256 * u;
        int d = id >> 4, e0 = (id & 15) * 4;
        float4 v = *reinterpret_cast<const float4*>(&W[(size_t)(h * DIN + d0 + d) * DE + e0]);
        Ws[d][e0] = v.x; Ws[d][e0 + 1] = v.y; Ws[d][e0 + 2] = v.z; Ws[d][e0 + 3] = v.w;
    }
    __syncthreads();
    #pragma unroll
    for (int u = 0; u < 2; ++u) {
        int id = t + 256 * u;
        int e = id >> 3, dc = (id & 7) * 8;
        short8 sh;
        #pragma unroll
        for (int j = 0; j < 8; ++j) sh[j] = (short)f2h(Ws[dc + j][e]);
        int n = z * 1024 + h * 64 + e;
        *reinterpret_cast<short8*>(&Wt[(size_t)n * DIN + d0 + dc]) = sh;
    }
}

// ---------------------------------------------------------------------------
// Kernel C: fused QKV projection GEMM (fp16), TRIPLE-buffered, ONE barrier
// per K-step. Q (x log2e), K fp16 [b][h][s][e]; V fp16 transposed [b][h][e][s],
// key-permuted within each 64-tile for attn's zero-shuffle PV.
// ---------------------------------------------------------------------------
__global__ __launch_bounds__(256)
void proj_kernel(const unsigned short* __restrict__ xf,
                 const unsigned short* __restrict__ Wt,
                 const float* __restrict__ bq, const float* __restrict__ bk,
                 const float* __restrict__ bv,
                 unsigned short* __restrict__ Qf, unsigned short* __restrict__ Kf,
                 unsigned short* __restrict__ Vt_g)
{
    __shared__ __attribute__((aligned(16))) unsigned short smem[6][128 * 32];  // 48 KB

    const int t = threadIdx.x;
    const int w = t >> 6, lane = t & 63, g = lane >> 4, li = lane & 15;
    const int wr = w >> 1, wc = w & 1;

    const int bid = blockIdx.x;
    const int gix = (bid & 7) * 96 + (bid >> 3);   // 768 = 8*96 bijective
    const int nt = gix % 24, mt = gix / 24;
    const int m0 = mt * 128, n0 = nt * 128;

    auto stage = [&](int set, int k0) {
        #pragma unroll
        for (int rnd = 0; rnd < 2; ++rnd) {
            const int U = rnd * 256 + t;
            const int p = U >> 3, i = U & 7, e = i ^ (p & 7);
            const int r = 2 * p + (e >> 2), c = (e & 3) * 8;
            const int ldso = (rnd * 256 + w * 64) * 8;
            gld16(smem[2 * set + 0] + ldso, xf + (size_t)(m0 + r) * DIN + k0 + c);
            gld16(smem[2 * set + 1] + ldso, Wt + (size_t)(n0 + r) * DIN + k0 + c);
        }
    };

    const f32x4 zero4 = {0.f, 0.f, 0.f, 0.f};
    f32x4 acc[4][4];
    #pragma unroll
    for (int i = 0; i < 4; ++i)
        #pragma unroll
        for (int j = 0; j < 4; ++j) acc[i][j] = zero4;

    stage(0, 0);
    stage(1, 32);

    int cur = 0;
    for (int i = 0; i < DIN / 32; ++i) {
        wait_vm4();                      // step i's 4 loads landed (i+1 in flight)
        __builtin_amdgcn_s_barrier();    // everyone's i-loads visible AND everyone
                                         // finished reading step i-1 (sequential code)
        short8 ah[4], bh[4];
        #pragma unroll
        for (int mf = 0; mf < 4; ++mf) ah[mf] = lds32(smem[2 * cur + 0], 64 * wr + 16 * mf + li, g);
        #pragma unroll
        for (int nf = 0; nf < 4; ++nf) bh[nf] = lds32(smem[2 * cur + 1], 64 * wc + 16 * nf + li, g);

        int kn = (i + 2) * 32;
        if (kn >= DIN) kn -= DIN;        // tail: dummy re-stage (never read)
        const int ns = (cur == 0) ? 2 : cur - 1;   // (cur+2)%3: held step i-1, free
        stage(ns, kn);                   // flies across barriers; overlaps MFMA

        __builtin_amdgcn_s_setprio(1);
        #pragma unroll
        for (int mf = 0; mf < 4; ++mf)
            #pragma unroll
            for (int nf = 0; nf < 4; ++nf)
                acc[mf][nf] = mfmaF(ah[mf], bh[nf], acc[mf][nf]);
        __builtin_amdgcn_s_setprio(0);

        cur = (cur == 2) ? 0 : cur + 1;
    }

    const int z = n0 >> 10;   // 0:Q 1:K 2:V (uniform per block)
    if (z < 2) {
        const bool isQ = (z == 0);
        const float* __restrict__ bias = isQ ? bq : bk;
        unsigned short* __restrict__ D = isQ ? Qf : Kf;
        const float qscl = isQ ? 1.4426950408889634f : 1.0f;   // log2(e) into Q
        #pragma unroll
        for (int nf = 0; nf < 4; ++nf) {
            const int n = n0 + 64 * wc + 16 * nf + li;
            const float bb = bias[n & 1023];
            const int hh = (n >> 6) & 15, e = n & 63;
            #pragma unroll
            for (int mf = 0; mf < 4; ++mf)
                #pragma unroll
                for (int r = 0; r < 4; ++r) {
                    const int m = m0 + 64 * wr + 16 * mf + 4 * g + r;
                    const int bat = m >> 11, s = m & 2047;
                    D[((size_t)(bat * NH + hh) * SEQ + s) * DE + e] =
                        f2h((acc[mf][nf][r] + bb) * qscl);
                }
        }
    } else {
        #pragma unroll
        for (int nf = 0; nf < 4; ++nf) {
            const int n = n0 + 64 * wc + 16 * nf + li;
            const float bb = bv[n & 1023];
            const int hh = (n >> 6) & 15, e = n & 63;
            #pragma unroll
            for (int mf = 0; mf < 4; ++mf) {
                const int m = m0 + 64 * wr + 16 * mf + 4 * g;
                const int bat = m >> 11, s0 = m & 2047;
                // key permutation within 64-tile: K4 -> pi (zero-shuffle PV)
                const int K4 = (s0 & 63) >> 2;
                const int pi = 8 * (K4 >> 3) + 2 * (K4 & 3) + ((K4 >> 2) & 1);
                const int ss = (s0 & ~63) | (pi << 2);
                ushort4_t pk;
                #pragma unroll
                for (int r = 0; r < 4; ++r) pk[r] = f2h(acc[mf][nf][r] + bb);
                *reinterpret_cast<ushort4_t*>(
                    &Vt_g[((size_t)(bat * NH + hh) * DE + e) * SEQ + ss]) = pk;
            }
        }
    }
}

// ---------------------------------------------------------------------------
// Kernel D: flash attention, SPLIT-K over KV (2 halves), R15 core unchanged:
// TRIPLE-buffered, ONE barrier per tile, deferred softmax (T15), raw
// v_exp_f32, zero-C MFMA init, defer-max, zero-shuffle PV, ones-MFMA row-sum.
// grid 512 = 2 blocks/CU co-resident (92 VGPR, NO launch-bounds min -- the
// R11/R12 spill lesson). Emits normalized partial o (f16) + L = m + log2(l).
// ---------------------------------------------------------------------------
__global__ __launch_bounds__(512)
void attn_kernel(const unsigned short* __restrict__ Qf,
                 const unsigned short* __restrict__ Kf,
                 const unsigned short* __restrict__ Vt_g,
                 unsigned short* __restrict__ po0,
                 unsigned short* __restrict__ po1,
                 float* __restrict__ Lb)
{
    __shared__ __attribute__((aligned(16))) unsigned short smem[6][64 * 64];  // 48 KB
    unsigned short* flat = &smem[0][0];

    const int t = threadIdx.x;
    const int w = t >> 6, lane = t & 63, g = lane >> 4, li = lane & 15;
    const int bid = blockIdx.x;
    const int gix = (bid & 7) * 64 + (bid >> 3);      // 512 = 8*64 bijective
    const int qt = gix & 7, h = (gix >> 3) & 15;
    const int bat = (gix >> 7) & 1, half = gix >> 8;
    const int kt0 = half * HALF_KV;
    const size_t bh = (size_t)(bat * NH + h) * SEQ;
    const size_t vb0 = (size_t)(bat * NH + h) * DE * SEQ;   // V^T base [e][s]

    // staging coords: 512 units of 16B cover one 64x64 f16 tile
    const int r = t >> 3, iu = t & 7, uu = iu ^ (r & 7);
    const int ldso = w * 512;                          // wave-uniform base (elems)

    // hoisted swizzled column slots (row&7 == li&7 for all frag rows)
    const int l7 = li & 7;
    const int sl0 = ((0 + g) ^ l7) << 3;               // ks=0
    const int sl1 = ((4 + g) ^ l7) << 3;               // ks=1

    // ---- stage Q (256 x 64 = 32 KB over bufs 0..3), hoist fragments ----
    #pragma unroll
    for (int rnd = 0; rnd < 4; ++rnd)
        gld16(flat + rnd * 4096 + ldso,
              Qf + (bh + qt * 256 + rnd * 64 + r) * DE + uu * 8);
    __syncthreads();

    short8 qh[2][2];   // [cb][ks]; wave w owns q rows 32w..32w+31
    #pragma unroll
    for (int cb = 0; cb < 2; ++cb) {
        const unsigned short* src = flat + (32 * w + 16 * cb + li) * 64;
        qh[cb][0] = *reinterpret_cast<const short8*>(src + sl0);
        qh[cb][1] = *reinterpret_cast<const short8*>(src + sl1);
    }
    __syncthreads();   // frags in regs; LDS free

    // ---- 2-deep prefetch prologue: tiles kt0, kt0+1 ----
    const unsigned short* kp = Kf + (bh + r) * DE + uu * 8;
    const unsigned short* vp = Vt_g + vb0 + (size_t)r * SEQ + uu * 8;
    auto stageKV = [&](int set, int tile) {
        gld16(smem[2 * set + 0] + ldso, kp + (size_t)tile * 64 * DE);
        gld16(smem[2 * set + 1] + ldso, vp + (size_t)tile * 64);
    };
    stageKV(0, kt0);
    stageKV(1, kt0 + 1);

    const f32x4 zero4 = {0.f, 0.f, 0.f, 0.f};
    const f32x4 ninf4 = {-3e38f, -3e38f, -3e38f, -3e38f};
    f32x4 accO[4][2];
    f32x4 accL[2];     // row-sum accumulator (all-ones MFMA); rescaled with accO
    #pragma unroll
    for (int vb = 0; vb < 4; ++vb) { accO[vb][0] = zero4; accO[vb][1] = zero4; }
    accL[0] = zero4; accL[1] = zero4;
    float m_c[2] = {-1e30f, -1e30f};

    short8 ones8;
    #pragma unroll
    for (int j = 0; j < 8; ++j) ones8[j] = (short)0x3C00;   // fp16 1.0

    // pipelined state (A/B alternation, rule #20 static names):
    // stX = scores of the tile whose softmax+PV is deferred; avX = its V frags.
    f32x4 stA[4][2], stB[4][2];
    short8 avP[2][4], avQ[2][4];
    #pragma unroll
    for (int rb = 0; rb < 4; ++rb) {
        stB[rb][0] = ninf4; stB[rb][1] = ninf4;   // first deferred softmax -> P=0
    }
    #pragma unroll
    for (int ks = 0; ks < 2; ++ks)
        #pragma unroll
        for (int vb = 0; vb < 4; ++vb) {
            short8 z8;
            #pragma unroll
            for (int j = 0; j < 8; ++j) z8[j] = 0;
            avP[ks][vb] = z8;
        }

    // one pipeline stage (ONE barrier): vmcnt(2) -> barrier -> ds_read K ->
    // stage(kt+2) -> softmax(stV) [VALU, fills ds latency] -> PV[kt-1] ->
    // QK[kt]->stC -> ds_read V (end; consumed next body).
#define BODY(kt, cs, stC, avC, stV, avV)                                        \
    {                                                                           \
        wait_vm2();                                                             \
        __builtin_amdgcn_s_barrier();                                           \
        const unsigned short* Ks = smem[2 * (cs) + 0];                          \
        const unsigned short* Vs = smem[2 * (cs) + 1];                          \
        short8 kf0[4], kf1[4];                                                  \
        _Pragma("unroll")                                                       \
        for (int rb = 0; rb < 4; ++rb) {                                        \
            kf0[rb] = *reinterpret_cast<const short8*>(Ks + (16 * rb + li) * 64 + sl0); \
            kf1[rb] = *reinterpret_cast<const short8*>(Ks + (16 * rb + li) * 64 + sl1); \
        }                                                                       \
        int tn = (kt) + 2;                                                      \
        if (tn >= kt0 + HALF_KV) tn -= HALF_KV;      /* dummy re-stage */       \
        const int ns = ((cs) == 0) ? 2 : (cs) - 1;   /* slot that held kt-1 */  \
        stageKV(ns, tn);                                                        \
        /* deferred softmax of tile kt-1 (registers only, hides ds latency) */  \
        int ppk[2][4][2];                                                       \
        _Pragma("unroll")                                                       \
        for (int cb = 0; cb < 2; ++cb) {                                        \
            float t0 = fmaxf(fmaxf(stV[0][cb][0], stV[0][cb][1]), stV[0][cb][2]);\
            float t1 = fmaxf(fmaxf(stV[0][cb][3], stV[1][cb][0]), stV[1][cb][1]);\
            float t2 = fmaxf(fmaxf(stV[1][cb][2], stV[1][cb][3]), stV[2][cb][0]);\
            float t3 = fmaxf(fmaxf(stV[2][cb][1], stV[2][cb][2]), stV[2][cb][3]);\
            float t4 = fmaxf(fmaxf(stV[3][cb][0], stV[3][cb][1]), stV[3][cb][2]);\
            float mx = fmaxf(fmaxf(fmaxf(t0, t1), stV[3][cb][3]),               \
                             fmaxf(fmaxf(t2, t3), t4));                         \
            if (__any(mx > m_c[cb] + 8.f)) {      /* rare: true rescale */      \
                mx = fmaxf(mx, __shfl_xor(mx, 16));                             \
                mx = fmaxf(mx, __shfl_xor(mx, 32));                             \
                const float mn = fmaxf(m_c[cb], mx);                            \
                const float scl = fexp2(m_c[cb] - mn);                          \
                _Pragma("unroll")                                               \
                for (int vb = 0; vb < 4; ++vb) accO[vb][cb] *= scl;             \
                accL[cb] *= scl;                                                \
                m_c[cb] = mn;                                                   \
            }                                                                   \
            const float mn = m_c[cb];                                           \
            _Pragma("unroll")                                                   \
            for (int rb = 0; rb < 4; ++rb) {                                    \
                const float p0 = fexp2(stV[rb][cb][0] - mn);                    \
                const float p1 = fexp2(stV[rb][cb][1] - mn);                    \
                const float p2 = fexp2(stV[rb][cb][2] - mn);                    \
                const float p3 = fexp2(stV[rb][cb][3] - mn);                    \
                ppk[cb][rb][0] = pkf16(p0, p1);                                 \
                ppk[cb][rb][1] = pkf16(p2, p3);                                 \
            }                                                                   \
        }                                                                       \
        /* PV[kt-1] (avV regs + fresh ppk) */                                   \
        __builtin_amdgcn_s_setprio(1);                                          \
        _Pragma("unroll")                                                       \
        for (int ks = 0; ks < 2; ++ks)                                          \
            _Pragma("unroll")                                                   \
            for (int cb = 0; cb < 2; ++cb) {                                    \
                union { int i[4]; short8 s; } u4;                               \
                u4.i[0] = ppk[cb][2 * ks][0];                                   \
                u4.i[1] = ppk[cb][2 * ks][1];                                   \
                u4.i[2] = ppk[cb][2 * ks + 1][0];                               \
                u4.i[3] = ppk[cb][2 * ks + 1][1];                               \
                _Pragma("unroll")                                               \
                for (int vb = 0; vb < 4; ++vb)                                  \
                    accO[vb][cb] = mfmaF(avV[ks][vb], u4.s, accO[vb][cb]);      \
                accL[cb] = mfmaF(ones8, u4.s, accL[cb]);                        \
            }                                                                   \
        /* QK[kt] -> stC (first MFMA takes the shared zero quad as C) */        \
        _Pragma("unroll")                                                       \
        for (int rb = 0; rb < 4; ++rb) {                                        \
            stC[rb][0] = mfmaF(kf0[rb], qh[0][0], zero4);                       \
            stC[rb][1] = mfmaF(kf0[rb], qh[1][0], zero4);                       \
            stC[rb][0] = mfmaF(kf1[rb], qh[0][1], stC[rb][0]);                  \
            stC[rb][1] = mfmaF(kf1[rb], qh[1][1], stC[rb][1]);                  \
        }                                                                       \
        __builtin_amdgcn_s_setprio(0);                                          \
        /* V[kt] -> avC at end (slot cs live until body kt+3's stage) */        \
        _Pragma("unroll")                                                       \
        for (int ks = 0; ks < 2; ++ks) {                                        \
            const int slv = ks ? sl1 : sl0;                                     \
            _Pragma("unroll")                                                   \
            for (int vb = 0; vb < 4; ++vb)                                      \
                avC[ks][vb] = *reinterpret_cast<const short8*>(Vs + (16 * vb + li) * 64 + slv); \
        }                                                                       \
    }

    int cs = 0;
    for (int k2 = 0; k2 < HALF_KV; k2 += 2) {
        BODY(kt0 + k2,     cs, stA, avQ, stB, avP);   // QK->stA; finish stB/avP
        cs = (cs == 2) ? 0 : cs + 1;
        BODY(kt0 + k2 + 1, cs, stB, avP, stA, avQ);   // QK->stB; finish stA/avQ
        cs = (cs == 2) ? 0 : cs + 1;
    }

    // ---- drain: softmax + PV for the final tile (stB/avP) ----
    #pragma unroll
    for (int cb = 0; cb < 2; ++cb) {
        float t0 = fmaxf(fmaxf(stB[0][cb][0], stB[0][cb][1]), stB[0][cb][2]);
        float t1 = fmaxf(fmaxf(stB[0][cb][3], stB[1][cb][0]), stB[1][cb][1]);
        float t2 = fmaxf(fmaxf(stB[1][cb][2], stB[1][cb][3]), stB[2][cb][0]);
        float t3 = fmaxf(fmaxf(stB[2][cb][1], stB[2][cb][2]), stB[2][cb][3]);
        float t4 = fmaxf(fmaxf(stB[3][cb][0], stB[3][cb][1]), stB[3][cb][2]);
        float mx = fmaxf(fmaxf(fmaxf(t0, t1), stB[3][cb][3]),
                         fmaxf(fmaxf(t2, t3), t4));
        if (__any(mx > m_c[cb] + 8.f)) {
            mx = fmaxf(mx, __shfl_xor(mx, 16));
            mx = fmaxf(mx, __shfl_xor(mx, 32));
            const float mn = fmaxf(m_c[cb], mx);
            const float scl = fexp2(m_c[cb] - mn);
            #pragma unroll
            for (int vb = 0; vb < 4; ++vb) accO[vb][cb] *= scl;
            accL[cb] *= scl;
            m_c[cb] = mn;
        }
        const float mn = m_c[cb];
        int ppkF[4][2];
        #pragma unroll
        for (int rb = 0; rb < 4; ++rb) {
            const float p0 = fexp2(stB[rb][cb][0] - mn);
            const float p1 = fexp2(stB[rb][cb][1] - mn);
            const float p2 = fexp2(stB[rb][cb][2] - mn);
            const float p3 = fexp2(stB[rb][cb][3] - mn);
            ppkF[rb][0] = pkf16(p0, p1);
            ppkF[rb][1] = pkf16(p2, p3);
        }
        __builtin_amdgcn_s_setprio(1);
        #pragma unroll
        for (int ks = 0; ks < 2; ++ks) {
            union { int i[4]; short8 s; } u4;
            u4.i[0] = ppkF[2 * ks][0];
            u4.i[1] = ppkF[2 * ks][1];
            u4.i[2] = ppkF[2 * ks + 1][0];
            u4.i[3] = ppkF[2 * ks + 1][1];
            #pragma unroll
            for (int vb = 0; vb < 4; ++vb)
                accO[vb][cb] = mfmaF(avP[ks][vb], u4.s, accO[vb][cb]);
            accL[cb] = mfmaF(ones8, u4.s, accL[cb]);
        }
        __builtin_amdgcn_s_setprio(0);
    }

    // ---- epilogue: normalized partial o (f16) + L = m + log2(l) ----
    unsigned short* __restrict__ po = half ? po1 : po0;
    #pragma unroll
    for (int cb = 0; cb < 2; ++cb) {
        const float invl = 1.0f / accL[cb][0];
        const int s = qt * 256 + 32 * w + 16 * cb + li;
        const int row = (bat * NH + h) * SEQ + s;
        #pragma unroll
        for (int vb = 0; vb < 4; ++vb) {
            ushort4_t pk;
            pk[0] = f2h(accO[vb][cb][0] * invl);
            pk[1] = f2h(accO[vb][cb][1] * invl);
            pk[2] = f2h(accO[vb][cb][2] * invl);
            pk[3] = f2h(accO[vb][cb][3] * invl);
            *reinterpret_cast<ushort4_t*>(&po[(size_t)row * 64 + 16 * vb + 4 * g]) = pk;
        }
        if (g == 0)
            Lb[half * NROW + row] = m_c[cb] + __log2f(accL[cb][0]);
    }
#undef BODY
}

// ---------------------------------------------------------------------------
// Kernel E: combine the two KV-halves.
// out = 0.125 * (o1*2^(L1-M) + o2*2^(L2-M)) / (2^(L1-M) + 2^(L2-M)).
// 2048 blocks x 256; 8 threads per row, 8 f16 elems each.
// ---------------------------------------------------------------------------
__global__ __launch_bounds__(256)
void combine_kernel(const unsigned short* __restrict__ po0,
                    const unsigned short* __restrict__ po1,
                    const float* __restrict__ Lb,
                    float* __restrict__ out)
{
    const int tid = threadIdx.x;
    const int row = blockIdx.x * 32 + (tid >> 3);
    const int e0 = (tid & 7) * 8;

    const float L1 = Lb[row], L2 = Lb[NROW + row];
    const float M = fmaxf(L1, L2);
    const float w1 = fexp2(L1 - M), w2 = fexp2(L2 - M);
    const float inv = 0.125f / (w1 + w2);
    const float a1 = w1 * inv, a2 = w2 * inv;

    short8 o1 = *reinterpret_cast<const short8*>(&po0[(size_t)row * 64 + e0]);
    short8 o2 = *reinterpret_cast<const short8*>(&po1[(size_t)row * 64 + e0]);

    const int bat = row >> 15, h = (row >> 11) & 15, s = row & 2047;
    float* dst = &out[((size_t)bat * SEQ + s) * (NH * DE) + h * DE + e0];

    float v[8];
    #pragma unroll
    for (int j = 0; j < 8; ++j)
        v[j] = a1 * h2f((unsigned short)o1[j]) + a2 * h2f((unsigned short)o2[j]);
    float4 r0, r1;
    r0.x = v[0]; r0.y = v[1]; r0.z = v[2]; r0.w = v[3];
    r1.x = v[4]; r1.y = v[5]; r1.z = v[6]; r1.w = v[7];
    *reinterpret_cast<float4*>(dst) = r0;
    *reinterpret_cast<float4*>(dst + 4) = r1;
}

extern "C" void kernel_launch(void* const* d_in, const int* in_sizes, int n_in,
                              void* d_out, int out_size, void* d_ws, size_t ws_size,
                              hipStream_t stream)
{
    (void)in_sizes; (void)n_in; (void)out_size; (void)ws_size;
    const float* x  = (const float*)d_in[0];
    const float* Wq = (const float*)d_in[1];
    const float* bq = (const float*)d_in[2];
    const float* Wk = (const float*)d_in[3];
    const float* bk = (const float*)d_in[4];
    const float* Wv = (const float*)d_in[5];
    const float* bv = (const float*)d_in[6];
    float* out = (float*)d_out;

    // d_out scratch: Wt fp16 (6.3 MB <= 16.8 MB), dead before combine writes.
    unsigned short* Wt = (unsigned short*)d_out;

    // d_ws (40.5 MB): [xf 8MB -> po0 after proj][Qf 8][Kf 8][Vt 8][po1 8][Lb .5]
    const size_t per = (size_t)BATCH * NH * SEQ * DE;   // 4 Mi elems = 8 MB fp16
    unsigned short* ws  = (unsigned short*)d_ws;
    unsigned short* xf  = ws;            // reused as po0 by attn (xf dead then)
    unsigned short* Qf  = ws + per;
    unsigned short* Kf  = ws + 2 * per;
    unsigned short* Vt  = ws + 3 * per;
    unsigned short* po1 = ws + 4 * per;
    float*          Lb  = (float*)(ws + 5 * per);
    unsigned short* po0 = xf;

    xcvt_kernel<<<2048, 256, 0, stream>>>(x, xf);
    wcvt_kernel<<<dim3(16, NH, 3), 256, 0, stream>>>(Wq, Wk, Wv, Wt);
    proj_kernel<<<768, 256, 0, stream>>>(xf, Wt, bq, bk, bv, Qf, Kf, Vt);
    attn_kernel<<<512, 512, 0, stream>>>(Qf, Kf, Vt, po0, po1, Lb);
    combine_kernel<<<2048, 256, 0, stream>>>(po0, po1, Lb, out);
}

// Round 17
// 94.483 us; speedup vs baseline: 1.1133x; 1.1133x over previous
//
#include <hip/hip_runtime.h>

#define BATCH 2
#define SEQ   2048
#define DIN   1024
#define NH    16
#define DE    64
#define NT_KV (SEQ / 64)

typedef __attribute__((ext_vector_type(8))) short short8;
typedef __attribute__((ext_vector_type(4))) float f32x4;
typedef __attribute__((ext_vector_type(4))) unsigned short ushort4_t;
typedef __attribute__((ext_vector_type(8))) _Float16 f16x8;

static __device__ __forceinline__ f32x4 mfmaF(short8 a, short8 b, f32x4 c) {
    return __builtin_amdgcn_mfma_f32_16x16x32_f16(
        __builtin_bit_cast(f16x8, a), __builtin_bit_cast(f16x8, b), c, 0, 0, 0);
}
// async global->LDS, 16B per lane; dest = wave-uniform base + lane*16
static __device__ __forceinline__ void gld16(unsigned short* l, const unsigned short* g) {
    __builtin_amdgcn_global_load_lds(
        (const __attribute__((address_space(1))) void*)g,
        (__attribute__((address_space(3))) void*)l, 16, 0, 0);
}
static __device__ __forceinline__ int pkf16(float a, float b) {
    return __builtin_bit_cast(int, __builtin_amdgcn_cvt_pkrtz(a, b));
}
static __device__ __forceinline__ unsigned short f2h(float f) {
    return __builtin_bit_cast(unsigned short, (_Float16)f);   // RNE
}
// raw v_exp_f32 (args are always <= 8 here; negative underflow -> 0 is wanted)
static __device__ __forceinline__ float fexp2(float x) {
    return __builtin_amdgcn_exp2f(x);
}
// counted waits (T4): keep prefetch in flight across barriers
static __device__ __forceinline__ void wait_vm1()  { asm volatile("s_waitcnt vmcnt(1)" ::: "memory"); }
static __device__ __forceinline__ void wait_vm4()  { asm volatile("s_waitcnt vmcnt(4)" ::: "memory"); }
// swizzled b128 read from a [R][32] f16 tile (row-pair scheme), proj only
static __device__ __forceinline__ short8 lds32(const unsigned short* buf, int row, int g) {
    int p = row >> 1, e = ((row & 1) << 2) | g;
    return *reinterpret_cast<const short8*>(buf + p * 64 + ((e ^ (p & 7)) << 3));
}

// ---------------------------------------------------------------------------
// Kernel A: convert x (fp32) -> fp16. 2048 blocks x 256, 8 elem/thr.
// ---------------------------------------------------------------------------
__global__ __launch_bounds__(256)
void xcvt_kernel(const float* __restrict__ x, unsigned short* __restrict__ xo)
{
    size_t i0 = ((size_t)blockIdx.x * 256 + threadIdx.x) * 8;
    float4 a = *reinterpret_cast<const float4*>(&x[i0]);
    float4 b = *reinterpret_cast<const float4*>(&x[i0 + 4]);
    float vv[8] = {a.x, a.y, a.z, a.w, b.x, b.y, b.z, b.w};
    short8 sh;
    #pragma unroll
    for (int j = 0; j < 8; ++j) sh[j] = (short)f2h(vv[j]);
    *reinterpret_cast<short8*>(&xo[i0]) = sh;
}

// ---------------------------------------------------------------------------
// Kernel B: W transpose + fp16 convert. Wt rows: n = z*1024 + h*64 + e.
// ---------------------------------------------------------------------------
__global__ __launch_bounds__(256)
void wcvt_kernel(const float* __restrict__ Wq, const float* __restrict__ Wk,
                 const float* __restrict__ Wv, unsigned short* __restrict__ Wt)
{
    const int dt = blockIdx.x, h = blockIdx.y, z = blockIdx.z;
    const float* __restrict__ W = (z == 0) ? Wq : (z == 1) ? Wk : Wv;
    __shared__ float Ws[64][65];
    const int t = threadIdx.x;
    const int d0 = dt * 64;
    #pragma unroll
    for (int u = 0; u < 4; ++u) {
        int id = t + 256 * u;
        int d = id >> 4, e0 = (id & 15) * 4;
        float4 v = *reinterpret_cast<const float4*>(&W[(size_t)(h * DIN + d0 + d) * DE + e0]);
        Ws[d][e0] = v.x; Ws[d][e0 + 1] = v.y; Ws[d][e0 + 2] = v.z; Ws[d][e0 + 3] = v.w;
    }
    __syncthreads();
    #pragma unroll
    for (int u = 0; u < 2; ++u) {
        int id = t + 256 * u;
        int e = id >> 3, dc = (id & 7) * 8;
        short8 sh;
        #pragma unroll
        for (int j = 0; j < 8; ++j) sh[j] = (short)f2h(Ws[dc + j][e]);
        int n = z * 1024 + h * 64 + e;
        *reinterpret_cast<short8*>(&Wt[(size_t)n * DIN + d0 + dc]) = sh;
    }
}

// ---------------------------------------------------------------------------
// Kernel C: fused QKV projection GEMM (fp16), TRIPLE-buffered, ONE barrier
// per K-step. Q (x log2e), K fp16 [b][h][s][e]; V fp16 transposed [b][h][e][s],
// key-permuted within each 64-tile for attn's zero-shuffle PV.
// ---------------------------------------------------------------------------
__global__ __launch_bounds__(256)
void proj_kernel(const unsigned short* __restrict__ xf,
                 const unsigned short* __restrict__ Wt,
                 const float* __restrict__ bq, const float* __restrict__ bk,
                 const float* __restrict__ bv,
                 unsigned short* __restrict__ Qf, unsigned short* __restrict__ Kf,
                 unsigned short* __restrict__ Vt_g)
{
    __shared__ __attribute__((aligned(16))) unsigned short smem[6][128 * 32];  // 48 KB

    const int t = threadIdx.x;
    const int w = t >> 6, lane = t & 63, g = lane >> 4, li = lane & 15;
    const int wr = w >> 1, wc = w & 1;

    const int bid = blockIdx.x;
    const int gix = (bid & 7) * 96 + (bid >> 3);   // 768 = 8*96 bijective
    const int nt = gix % 24, mt = gix / 24;
    const int m0 = mt * 128, n0 = nt * 128;

    auto stage = [&](int set, int k0) {
        #pragma unroll
        for (int rnd = 0; rnd < 2; ++rnd) {
            const int U = rnd * 256 + t;
            const int p = U >> 3, i = U & 7, e = i ^ (p & 7);
            const int r = 2 * p + (e >> 2), c = (e & 3) * 8;
            const int ldso = (rnd * 256 + w * 64) * 8;
            gld16(smem[2 * set + 0] + ldso, xf + (size_t)(m0 + r) * DIN + k0 + c);
            gld16(smem[2 * set + 1] + ldso, Wt + (size_t)(n0 + r) * DIN + k0 + c);
        }
    };

    const f32x4 zero4 = {0.f, 0.f, 0.f, 0.f};
    f32x4 acc[4][4];
    #pragma unroll
    for (int i = 0; i < 4; ++i)
        #pragma unroll
        for (int j = 0; j < 4; ++j) acc[i][j] = zero4;

    stage(0, 0);
    stage(1, 32);

    int cur = 0;
    for (int i = 0; i < DIN / 32; ++i) {
        wait_vm4();                      // step i's 4 loads landed (i+1 in flight)
        __builtin_amdgcn_s_barrier();    // everyone's i-loads visible AND everyone
                                         // finished reading step i-1 (sequential code)
        short8 ah[4], bh[4];
        #pragma unroll
        for (int mf = 0; mf < 4; ++mf) ah[mf] = lds32(smem[2 * cur + 0], 64 * wr + 16 * mf + li, g);
        #pragma unroll
        for (int nf = 0; nf < 4; ++nf) bh[nf] = lds32(smem[2 * cur + 1], 64 * wc + 16 * nf + li, g);

        int kn = (i + 2) * 32;
        if (kn >= DIN) kn -= DIN;        // tail: dummy re-stage (never read)
        const int ns = (cur == 0) ? 2 : cur - 1;   // (cur+2)%3: held step i-1, free
        stage(ns, kn);                   // flies across barriers; overlaps MFMA

        __builtin_amdgcn_s_setprio(1);
        #pragma unroll
        for (int mf = 0; mf < 4; ++mf)
            #pragma unroll
            for (int nf = 0; nf < 4; ++nf)
                acc[mf][nf] = mfmaF(ah[mf], bh[nf], acc[mf][nf]);
        __builtin_amdgcn_s_setprio(0);

        cur = (cur == 2) ? 0 : cur + 1;
    }

    const int z = n0 >> 10;   // 0:Q 1:K 2:V (uniform per block)
    if (z < 2) {
        const bool isQ = (z == 0);
        const float* __restrict__ bias = isQ ? bq : bk;
        unsigned short* __restrict__ D = isQ ? Qf : Kf;
        const float qscl = isQ ? 1.4426950408889634f : 1.0f;   // log2(e) into Q
        #pragma unroll
        for (int nf = 0; nf < 4; ++nf) {
            const int n = n0 + 64 * wc + 16 * nf + li;
            const float bb = bias[n & 1023];
            const int hh = (n >> 6) & 15, e = n & 63;
            #pragma unroll
            for (int mf = 0; mf < 4; ++mf)
                #pragma unroll
                for (int r = 0; r < 4; ++r) {
                    const int m = m0 + 64 * wr + 16 * mf + 4 * g + r;
                    const int bat = m >> 11, s = m & 2047;
                    D[((size_t)(bat * NH + hh) * SEQ + s) * DE + e] =
                        f2h((acc[mf][nf][r] + bb) * qscl);
                }
        }
    } else {
        #pragma unroll
        for (int nf = 0; nf < 4; ++nf) {
            const int n = n0 + 64 * wc + 16 * nf + li;
            const float bb = bv[n & 1023];
            const int hh = (n >> 6) & 15, e = n & 63;
            #pragma unroll
            for (int mf = 0; mf < 4; ++mf) {
                const int m = m0 + 64 * wr + 16 * mf + 4 * g;
                const int bat = m >> 11, s0 = m & 2047;
                // key permutation within 64-tile: K4 -> pi (zero-shuffle PV)
                const int K4 = (s0 & 63) >> 2;
                const int pi = 8 * (K4 >> 3) + 2 * (K4 & 3) + ((K4 >> 2) & 1);
                const int ss = (s0 & ~63) | (pi << 2);
                ushort4_t pk;
                #pragma unroll
                for (int r = 0; r < 4; ++r) pk[r] = f2h(acc[mf][nf][r] + bb);
                *reinterpret_cast<ushort4_t*>(
                    &Vt_g[((size_t)(bat * NH + hh) * DE + e) * SEQ + ss]) = pk;
            }
        }
    }
}

// ---------------------------------------------------------------------------
// Kernel D: flash attention, 16 waves x 16 q-rows = 256-row q-tile in ONE
// 1024-thread workgroup (R12 showed 44% occupancy is achievable this way;
// R9/R16 showed two separate workgroups never co-reside). R14 core: triple
// buffer, ONE barrier/tile, pipelined PV (one tile behind), raw v_exp_f32,
// zero-C MFMA init, defer-max fast path, zero-shuffle PV, ones-MFMA row-sum.
// Shared K/V staging: 1 gld16 per lane per tile (waves 0-7 K, 8-15 V),
// vmcnt(1). NO launch-bounds min (R11/R12 spill lesson): 1024 threads alone
// forces VGPR<=128; per-wave state (~110) fits. grid 256, XCD-swizzled.
// ---------------------------------------------------------------------------
__global__ __launch_bounds__(1024)
void attn_kernel(const unsigned short* __restrict__ Qf,
                 const unsigned short* __restrict__ Kf,
                 const unsigned short* __restrict__ Vt_g,
                 float* __restrict__ out)
{
    // 3 slots x 16KB (K 8KB + V 8KB) = 48 KB; Q staging reuses slots 0-1.
    __shared__ __attribute__((aligned(16))) unsigned short smem[3 * 8192];

    const int t = threadIdx.x;                        // 1024 threads, 16 waves
    const int w = t >> 6, lane = t & 63, g = lane >> 4, li = lane & 15;
    const int bid = blockIdx.x;
    const int gix = (bid & 7) * 32 + (bid >> 3);      // 256 = 8*32 bijective
    const int qp = gix & 7, h = (gix >> 3) & 15, bat = gix >> 7;
    const size_t bh = (size_t)(bat * NH + h) * SEQ;
    const size_t vb0 = (size_t)(bat * NH + h) * DE * SEQ;   // V^T base [e][s]

    // KV staging coords: lanes 0-511 stage K, 512-1023 stage V; 1 load/lane.
    const int tk = t & 511;
    const int rkv = tk >> 3, ukv = (tk & 7) ^ (rkv & 7);
    const bool isK = (w < 8);
    const int ldsoKV = (isK ? (w * 512) : (4096 + (w - 8) * 512));

    // hoisted swizzled column slots (row&7 == li&7 for all frag rows)
    const int l7 = li & 7;
    const int sl0 = ((0 + g) ^ l7) << 3;               // ks=0
    const int sl1 = ((4 + g) ^ l7) << 3;               // ks=1

    // ---- stage Q (256 x 64 = 32 KB over slots 0-1), hoist fragments ----
    {
        const int rq = t >> 3, uq = (t & 7) ^ (rq & 7);
        #pragma unroll
        for (int rnd = 0; rnd < 2; ++rnd)
            gld16(smem + rnd * 8192 + w * 512,
                  Qf + (bh + qp * 256 + rnd * 128 + rq) * DE + uq * 8);
    }
    __syncthreads();

    short8 qh[2];   // [ks]; wave w owns q rows 16w..16w+15
    {
        const unsigned short* src = smem + (16 * w + li) * 64;
        qh[0] = *reinterpret_cast<const short8*>(src + sl0);
        qh[1] = *reinterpret_cast<const short8*>(src + sl1);
    }
    __syncthreads();   // frags in regs; LDS free

    // ---- 2-deep prefetch prologue: tiles 0 and 1 (1 load per lane each) ----
    const unsigned short* kp = Kf + (bh + rkv) * DE + ukv * 8;
    const unsigned short* vp = Vt_g + vb0 + (size_t)rkv * SEQ + ukv * 8;
    auto stageKV = [&](int slot, int tile) {
        if (isK) gld16(smem + slot * 8192 + ldsoKV, kp + (size_t)tile * 64 * DE);
        else     gld16(smem + slot * 8192 + ldsoKV, vp + (size_t)tile * 64);
    };
    stageKV(0, 0);
    stageKV(1, 1);

    const f32x4 zero4 = {0.f, 0.f, 0.f, 0.f};
    f32x4 accO[4];
    f32x4 accL;        // row-sum accumulator (all-ones MFMA); rescaled with accO
    #pragma unroll
    for (int vb = 0; vb < 4; ++vb) accO[vb] = zero4;
    accL = zero4;
    float m_c = -1e30f;

    short8 ones8;
    #pragma unroll
    for (int j = 0; j < 8; ++j) ones8[j] = (short)0x3C00;   // fp16 1.0

    // pipelined P/V register state (A/B alternation, rule #20: static names)
    int ppkP[4][2] = {};         // "prev" role first iter: P = 0 -> PV adds 0
    int ppkQ[4][2];
    short8 avP[2][4], avQ[2][4];
    #pragma unroll
    for (int ks = 0; ks < 2; ++ks)
        #pragma unroll
        for (int vb = 0; vb < 4; ++vb) {
            short8 z8;
            #pragma unroll
            for (int j = 0; j < 8; ++j) z8[j] = 0;
            avP[ks][vb] = z8;
        }

    // one pipeline stage (ONE barrier): vmcnt(1) -> barrier -> ds_read K ->
    // stage(kt+2 into slot that held kt-1) -> PV[kt-1] -> QK[kt] -> softmax
    // -> ds_read V[kt] (end; consumed next body).
#define BODY(kt, cs, ppkC, avC, ppkV, avV)                                      \
    {                                                                           \
        wait_vm1();                                                             \
        __builtin_amdgcn_s_barrier();                                           \
        const unsigned short* Ks = smem + (cs) * 8192;                          \
        const unsigned short* Vs = Ks + 4096;                                   \
        short8 kf0[4], kf1[4];                                                  \
        _Pragma("unroll")                                                       \
        for (int rb = 0; rb < 4; ++rb) {                                        \
            kf0[rb] = *reinterpret_cast<const short8*>(Ks + (16 * rb + li) * 64 + sl0); \
            kf1[rb] = *reinterpret_cast<const short8*>(Ks + (16 * rb + li) * 64 + sl1); \
        }                                                                       \
        int tn = (kt) + 2;                                                      \
        if (tn >= NT_KV) tn -= NT_KV;                                           \
        const int ns = ((cs) == 0) ? 2 : (cs) - 1;   /* slot that held kt-1 */  \
        stageKV(ns, tn);                                                        \
        /* PV[kt-1]: registers only -> covers the ds_read latency above */      \
        __builtin_amdgcn_s_setprio(1);                                          \
        _Pragma("unroll")                                                       \
        for (int ks = 0; ks < 2; ++ks) {                                        \
            union { int i[4]; short8 s; } u4;                                   \
            u4.i[0] = ppkV[2 * ks][0];                                          \
            u4.i[1] = ppkV[2 * ks][1];                                          \
            u4.i[2] = ppkV[2 * ks + 1][0];                                      \
            u4.i[3] = ppkV[2 * ks + 1][1];                                      \
            _Pragma("unroll")                                                   \
            for (int vb = 0; vb < 4; ++vb)                                      \
                accO[vb] = mfmaF(avV[ks][vb], u4.s, accO[vb]);                  \
            accL = mfmaF(ones8, u4.s, accL);                                    \
        }                                                                       \
        /* QK[kt] (first MFMA takes the shared zero quad as C) */               \
        f32x4 st[4];                                                            \
        _Pragma("unroll")                                                       \
        for (int rb = 0; rb < 4; ++rb) {                                        \
            st[rb] = mfmaF(kf0[rb], qh[0], zero4);                              \
            st[rb] = mfmaF(kf1[rb], qh[1], st[rb]);                             \
        }                                                                       \
        __builtin_amdgcn_s_setprio(0);                                          \
        /* softmax[kt] (base-2, Q pre-scaled), defer-max fast path */           \
        {                                                                       \
            float t0 = fmaxf(fmaxf(st[0][0], st[0][1]), st[0][2]);              \
            float t1 = fmaxf(fmaxf(st[0][3], st[1][0]), st[1][1]);              \
            float t2 = fmaxf(fmaxf(st[1][2], st[1][3]), st[2][0]);              \
            float t3 = fmaxf(fmaxf(st[2][1], st[2][2]), st[2][3]);              \
            float t4 = fmaxf(fmaxf(st[3][0], st[3][1]), st[3][2]);              \
            float mx = fmaxf(fmaxf(fmaxf(t0, t1), st[3][3]),                    \
                             fmaxf(fmaxf(t2, t3), t4));                         \
            if (__any(mx > m_c + 8.f)) {          /* rare: true rescale */      \
                mx = fmaxf(mx, __shfl_xor(mx, 16));                             \
                mx = fmaxf(mx, __shfl_xor(mx, 32));                             \
                const float mn = fmaxf(m_c, mx);                                \
                const float scl = fexp2(m_c - mn);                              \
                _Pragma("unroll")                                               \
                for (int vb = 0; vb < 4; ++vb) accO[vb] *= scl;                 \
                accL *= scl;                                                    \
                m_c = mn;                                                       \
            }                                                                   \
            const float mn = m_c;                                               \
            _Pragma("unroll")                                                   \
            for (int rb = 0; rb < 4; ++rb) {                                    \
                const float p0 = fexp2(st[rb][0] - mn);                         \
                const float p1 = fexp2(st[rb][1] - mn);                         \
                const float p2 = fexp2(st[rb][2] - mn);                         \
                const float p3 = fexp2(st[rb][3] - mn);                         \
                ppkC[rb][0] = pkf16(p0, p1);                                    \
                ppkC[rb][1] = pkf16(p2, p3);                                    \
            }                                                                   \
        }                                                                       \
        /* V[kt] -> avC at end (slot cs live until body kt+3's stage) */        \
        _Pragma("unroll")                                                       \
        for (int ks = 0; ks < 2; ++ks) {                                        \
            const int slv = ks ? sl1 : sl0;                                     \
            _Pragma("unroll")                                                   \
            for (int vb = 0; vb < 4; ++vb)                                      \
                avC[ks][vb] = *reinterpret_cast<const short8*>(Vs + (16 * vb + li) * 64 + slv); \
        }                                                                       \
    }

    int cs = 0;
    for (int kt = 0; kt < NT_KV; kt += 2) {
        BODY(kt,     cs, ppkQ, avQ, ppkP, avP);   // writes Q-state, PV uses P
        cs = (cs == 2) ? 0 : cs + 1;
        BODY(kt + 1, cs, ppkP, avP, ppkQ, avQ);   // writes P-state, PV uses Q
        cs = (cs == 2) ? 0 : cs + 1;
    }

    // ---- drain: final PV with the last (P) state ----
    __builtin_amdgcn_s_setprio(1);
    #pragma unroll
    for (int ks = 0; ks < 2; ++ks) {
        union { int i[4]; short8 s; } u4;
        u4.i[0] = ppkP[2 * ks][0];
        u4.i[1] = ppkP[2 * ks][1];
        u4.i[2] = ppkP[2 * ks + 1][0];
        u4.i[3] = ppkP[2 * ks + 1][1];
        #pragma unroll
        for (int vb = 0; vb < 4; ++vb)
            accO[vb] = mfmaF(avP[ks][vb], u4.s, accO[vb]);
        accL = mfmaF(ones8, u4.s, accL);
    }
    __builtin_amdgcn_s_setprio(0);

    // ---- epilogue: out[b][s][h*64+vd] = O^T / (l * 8) ----
    {
        const float invl = 0.125f / accL[0];
        const int s = qp * 256 + 16 * w + li;
        #pragma unroll
        for (int vb = 0; vb < 4; ++vb) {
            float4 o;
            o.x = accO[vb][0] * invl;
            o.y = accO[vb][1] * invl;
            o.z = accO[vb][2] * invl;
            o.w = accO[vb][3] * invl;
            const int vd = 16 * vb + 4 * g;
            *reinterpret_cast<float4*>(
                &out[((size_t)bat * SEQ + s) * (NH * DE) + h * DE + vd]) = o;
        }
    }
#undef BODY
}

extern "C" void kernel_launch(void* const* d_in, const int* in_sizes, int n_in,
                              void* d_out, int out_size, void* d_ws, size_t ws_size,
                              hipStream_t stream)
{
    (void)in_sizes; (void)n_in; (void)out_size; (void)ws_size;
    const float* x  = (const float*)d_in[0];
    const float* Wq = (const float*)d_in[1];
    const float* bq = (const float*)d_in[2];
    const float* Wk = (const float*)d_in[3];
    const float* bk = (const float*)d_in[4];
    const float* Wv = (const float*)d_in[5];
    const float* bv = (const float*)d_in[6];
    float* out = (float*)d_out;

    // d_out scratch: Wt fp16 (6.3 MB <= 16.8 MB), dead before attn writes.
    unsigned short* Wt = (unsigned short*)d_out;

    // d_ws: [xf 8MB][Qf 8][Kf 8][Vt 8]
    const size_t per = (size_t)BATCH * NH * SEQ * DE;   // 4 Mi elems = 8 MB fp16
    unsigned short* ws = (unsigned short*)d_ws;
    unsigned short* xf = ws;
    unsigned short* Qf = ws + per;
    unsigned short* Kf = ws + 2 * per;
    unsigned short* Vt = ws + 3 * per;

    xcvt_kernel<<<2048, 256, 0, stream>>>(x, xf);
    wcvt_kernel<<<dim3(16, NH, 3), 256, 0, stream>>>(Wq, Wk, Wv, Wt);
    proj_kernel<<<768, 256, 0, stream>>>(xf, Wt, bq, bk, bv, Qf, Kf, Vt);
    attn_kernel<<<256, 1024, 0, stream>>>(Qf, Kf, Vt, out);
}

// Round 18
// 92.621 us; speedup vs baseline: 1.1357x; 1.0201x over previous
//
#include <hip/hip_runtime.h>

#define BATCH 2
#define SEQ   2048
#define DIN   1024
#define NH    16
#define DE    64
#define NT_KV (SEQ / 64)

typedef __attribute__((ext_vector_type(8))) short short8;
typedef __attribute__((ext_vector_type(4))) float f32x4;
typedef __attribute__((ext_vector_type(4))) unsigned short ushort4_t;
typedef __attribute__((ext_vector_type(8))) _Float16 f16x8;

static __device__ __forceinline__ f32x4 mfmaF(short8 a, short8 b, f32x4 c) {
    return __builtin_amdgcn_mfma_f32_16x16x32_f16(
        __builtin_bit_cast(f16x8, a), __builtin_bit_cast(f16x8, b), c, 0, 0, 0);
}
// async global->LDS, 16B per lane; dest = wave-uniform base + lane*16
static __device__ __forceinline__ void gld16(unsigned short* l, const unsigned short* g) {
    __builtin_amdgcn_global_load_lds(
        (const __attribute__((address_space(1))) void*)g,
        (__attribute__((address_space(3))) void*)l, 16, 0, 0);
}
static __device__ __forceinline__ int pkf16(float a, float b) {
    return __builtin_bit_cast(int, __builtin_amdgcn_cvt_pkrtz(a, b));
}
static __device__ __forceinline__ unsigned short f2h(float f) {
    return __builtin_bit_cast(unsigned short, (_Float16)f);   // RNE
}
// raw v_exp_f32 (args are always <= 8 here; negative underflow -> 0 is wanted)
static __device__ __forceinline__ float fexp2(float x) {
    return __builtin_amdgcn_exp2f(x);
}
// counted waits (T4): keep prefetch in flight across barriers
static __device__ __forceinline__ void wait_vm2()  { asm volatile("s_waitcnt vmcnt(2)" ::: "memory"); }
static __device__ __forceinline__ void wait_vm4()  { asm volatile("s_waitcnt vmcnt(4)" ::: "memory"); }
// swizzled b128 read from a [R][32] f16 tile (row-pair scheme), proj only
static __device__ __forceinline__ short8 lds32(const unsigned short* buf, int row, int g) {
    int p = row >> 1, e = ((row & 1) << 2) | g;
    return *reinterpret_cast<const short8*>(buf + p * 64 + ((e ^ (p & 7)) << 3));
}

// ---------------------------------------------------------------------------
// Kernel A: convert x (fp32) -> fp16. 2048 blocks x 256, 8 elem/thr.
// ---------------------------------------------------------------------------
__global__ __launch_bounds__(256)
void xcvt_kernel(const float* __restrict__ x, unsigned short* __restrict__ xo)
{
    size_t i0 = ((size_t)blockIdx.x * 256 + threadIdx.x) * 8;
    float4 a = *reinterpret_cast<const float4*>(&x[i0]);
    float4 b = *reinterpret_cast<const float4*>(&x[i0 + 4]);
    float vv[8] = {a.x, a.y, a.z, a.w, b.x, b.y, b.z, b.w};
    short8 sh;
    #pragma unroll
    for (int j = 0; j < 8; ++j) sh[j] = (short)f2h(vv[j]);
    *reinterpret_cast<short8*>(&xo[i0]) = sh;
}

// ---------------------------------------------------------------------------
// Kernel B: W transpose + fp16 convert. Wt rows: n = z*1024 + h*64 + e.
// ---------------------------------------------------------------------------
__global__ __launch_bounds__(256)
void wcvt_kernel(const float* __restrict__ Wq, const float* __restrict__ Wk,
                 const float* __restrict__ Wv, unsigned short* __restrict__ Wt)
{
    const int dt = blockIdx.x, h = blockIdx.y, z = blockIdx.z;
    const float* __restrict__ W = (z == 0) ? Wq : (z == 1) ? Wk : Wv;
    __shared__ float Ws[64][65];
    const int t = threadIdx.x;
    const int d0 = dt * 64;
    #pragma unroll
    for (int u = 0; u < 4; ++u) {
        int id = t + 256 * u;
        int d = id >> 4, e0 = (id & 15) * 4;
        float4 v = *reinterpret_cast<const float4*>(&W[(size_t)(h * DIN + d0 + d) * DE + e0]);
        Ws[d][e0] = v.x; Ws[d][e0 + 1] = v.y; Ws[d][e0 + 2] = v.z; Ws[d][e0 + 3] = v.w;
    }
    __syncthreads();
    #pragma unroll
    for (int u = 0; u < 2; ++u) {
        int id = t + 256 * u;
        int e = id >> 3, dc = (id & 7) * 8;
        short8 sh;
        #pragma unroll
        for (int j = 0; j < 8; ++j) sh[j] = (short)f2h(Ws[dc + j][e]);
        int n = z * 1024 + h * 64 + e;
        *reinterpret_cast<short8*>(&Wt[(size_t)n * DIN + d0 + dc]) = sh;
    }
}

// ---------------------------------------------------------------------------
// Kernel C: fused QKV projection GEMM (fp16), TRIPLE-buffered, ONE barrier
// per K-step. Q (x log2e), K fp16 [b][h][s][e]; V fp16 transposed [b][h][e][s],
// key-permuted within each 64-tile for attn's zero-shuffle PV.
// ---------------------------------------------------------------------------
__global__ __launch_bounds__(256)
void proj_kernel(const unsigned short* __restrict__ xf,
                 const unsigned short* __restrict__ Wt,
                 const float* __restrict__ bq, const float* __restrict__ bk,
                 const float* __restrict__ bv,
                 unsigned short* __restrict__ Qf, unsigned short* __restrict__ Kf,
                 unsigned short* __restrict__ Vt_g)
{
    __shared__ __attribute__((aligned(16))) unsigned short smem[6][128 * 32];  // 48 KB

    const int t = threadIdx.x;
    const int w = t >> 6, lane = t & 63, g = lane >> 4, li = lane & 15;
    const int wr = w >> 1, wc = w & 1;

    const int bid = blockIdx.x;
    const int gix = (bid & 7) * 96 + (bid >> 3);   // 768 = 8*96 bijective
    const int nt = gix % 24, mt = gix / 24;
    const int m0 = mt * 128, n0 = nt * 128;

    auto stage = [&](int set, int k0) {
        #pragma unroll
        for (int rnd = 0; rnd < 2; ++rnd) {
            const int U = rnd * 256 + t;
            const int p = U >> 3, i = U & 7, e = i ^ (p & 7);
            const int r = 2 * p + (e >> 2), c = (e & 3) * 8;
            const int ldso = (rnd * 256 + w * 64) * 8;
            gld16(smem[2 * set + 0] + ldso, xf + (size_t)(m0 + r) * DIN + k0 + c);
            gld16(smem[2 * set + 1] + ldso, Wt + (size_t)(n0 + r) * DIN + k0 + c);
        }
    };

    const f32x4 zero4 = {0.f, 0.f, 0.f, 0.f};
    f32x4 acc[4][4];
    #pragma unroll
    for (int i = 0; i < 4; ++i)
        #pragma unroll
        for (int j = 0; j < 4; ++j) acc[i][j] = zero4;

    stage(0, 0);
    stage(1, 32);

    int cur = 0;
    for (int i = 0; i < DIN / 32; ++i) {
        wait_vm4();                      // step i's 4 loads landed (i+1 in flight)
        __builtin_amdgcn_s_barrier();    // everyone's i-loads visible AND everyone
                                         // finished reading step i-1 (sequential code)
        short8 ah[4], bh[4];
        #pragma unroll
        for (int mf = 0; mf < 4; ++mf) ah[mf] = lds32(smem[2 * cur + 0], 64 * wr + 16 * mf + li, g);
        #pragma unroll
        for (int nf = 0; nf < 4; ++nf) bh[nf] = lds32(smem[2 * cur + 1], 64 * wc + 16 * nf + li, g);

        int kn = (i + 2) * 32;
        if (kn >= DIN) kn -= DIN;        // tail: dummy re-stage (never read)
        const int ns = (cur == 0) ? 2 : cur - 1;   // (cur+2)%3: held step i-1, free
        stage(ns, kn);                   // flies across barriers; overlaps MFMA

        __builtin_amdgcn_s_setprio(1);
        #pragma unroll
        for (int mf = 0; mf < 4; ++mf)
            #pragma unroll
            for (int nf = 0; nf < 4; ++nf)
                acc[mf][nf] = mfmaF(ah[mf], bh[nf], acc[mf][nf]);
        __builtin_amdgcn_s_setprio(0);

        cur = (cur == 2) ? 0 : cur + 1;
    }

    const int z = n0 >> 10;   // 0:Q 1:K 2:V (uniform per block)
    if (z < 2) {
        const bool isQ = (z == 0);
        const float* __restrict__ bias = isQ ? bq : bk;
        unsigned short* __restrict__ D = isQ ? Qf : Kf;
        const float qscl = isQ ? 1.4426950408889634f : 1.0f;   // log2(e) into Q
        #pragma unroll
        for (int nf = 0; nf < 4; ++nf) {
            const int n = n0 + 64 * wc + 16 * nf + li;
            const float bb = bias[n & 1023];
            const int hh = (n >> 6) & 15, e = n & 63;
            #pragma unroll
            for (int mf = 0; mf < 4; ++mf)
                #pragma unroll
                for (int r = 0; r < 4; ++r) {
                    const int m = m0 + 64 * wr + 16 * mf + 4 * g + r;
                    const int bat = m >> 11, s = m & 2047;
                    D[((size_t)(bat * NH + hh) * SEQ + s) * DE + e] =
                        f2h((acc[mf][nf][r] + bb) * qscl);
                }
        }
    } else {
        #pragma unroll
        for (int nf = 0; nf < 4; ++nf) {
            const int n = n0 + 64 * wc + 16 * nf + li;
            const float bb = bv[n & 1023];
            const int hh = (n >> 6) & 15, e = n & 63;
            #pragma unroll
            for (int mf = 0; mf < 4; ++mf) {
                const int m = m0 + 64 * wr + 16 * mf + 4 * g;
                const int bat = m >> 11, s0 = m & 2047;
                // key permutation within 64-tile: K4 -> pi (zero-shuffle PV)
                const int K4 = (s0 & 63) >> 2;
                const int pi = 8 * (K4 >> 3) + 2 * (K4 & 3) + ((K4 >> 2) & 1);
                const int ss = (s0 & ~63) | (pi << 2);
                ushort4_t pk;
                #pragma unroll
                for (int r = 0; r < 4; ++r) pk[r] = f2h(acc[mf][nf][r] + bb);
                *reinterpret_cast<ushort4_t*>(
                    &Vt_g[((size_t)(bat * NH + hh) * DE + e) * SEQ + ss]) = pk;
            }
        }
    }
}

// ---------------------------------------------------------------------------
// Kernel D: flash attention, 16 waves in ONE 1024-thread workgroup split into
// TWO independent KV-groups: waves 0-7 do tiles 0-15, waves 8-15 do tiles
// 16-31, both over the same 256 q-rows (32 q-rows/wave, cb=2). Each tile is
// read by only 8 waves -> LDS read traffic per tile halves vs R17 (the
// measured 81%-busy bottleneck). Groups are barrier-aligned but data-
// independent -> group A's softmax VALU overlaps group B's MFMA. Immediate
// softmax+PV (all LDS reads complete before the next barrier -> race-free).
// Triple buffer (3 x 32 KB slots), ONE barrier/tile, raw v_exp_f32, zero-C
// MFMA init, defer-max, zero-shuffle PV, ones-MFMA row-sum. Epilogue:
// group 1 parks (accO,l,m) in LDS (stride 37 = conflict-free), group 0 does
// the exact log-sum-exp merge and writes out. grid 256, XCD-swizzled.
// ---------------------------------------------------------------------------
__global__ __launch_bounds__(1024)
void attn_kernel(const unsigned short* __restrict__ Qf,
                 const unsigned short* __restrict__ Kf,
                 const unsigned short* __restrict__ Vt_g,
                 float* __restrict__ out)
{
    // 3 slots x (2 groups x (K 8KB + V 8KB)) = 96 KB
    __shared__ __attribute__((aligned(16))) unsigned short smem[3 * 16384];

    const int t = threadIdx.x;                        // 1024 threads, 16 waves
    const int w = t >> 6, lane = t & 63, g = lane >> 4, li = lane & 15;
    const int grp = w >> 3, wg = w & 7;               // KV-group, wave-in-group
    const int bid = blockIdx.x;
    const int gix = (bid & 7) * 32 + (bid >> 3);      // 256 = 8*32 bijective
    const int qp = gix & 7, h = (gix >> 3) & 15, bat = gix >> 7;
    const size_t bh = (size_t)(bat * NH + h) * SEQ;
    const size_t vb0 = (size_t)(bat * NH + h) * DE * SEQ;   // V^T base [e][s]
    const int kt0 = grp * 16;                         // group's KV tile range

    // KV staging coords: each group's 512 lanes cover one 64x64 tile; each
    // lane stages 16B of K and 16B of V per tile.
    const int tk = t & 511;
    const int rkv = tk >> 3, ukv = (tk & 7) ^ (rkv & 7);
    const int ldkv = wg * 512;                        // elems within group region

    // hoisted swizzled column slots (row&7 == li&7 for all frag rows)
    const int l7 = li & 7;
    const int sl0 = ((0 + g) ^ l7) << 3;              // ks=0
    const int sl1 = ((4 + g) ^ l7) << 3;              // ks=1

    // ---- stage Q (256 x 64 = 32 KB, linear in slot 0), hoist fragments ----
    {
        const int rq = t >> 3, uq = (t & 7) ^ (rq & 7);
        #pragma unroll
        for (int rnd = 0; rnd < 2; ++rnd)
            gld16(smem + rnd * 8192 + w * 512,
                  Qf + (bh + qp * 256 + rnd * 128 + rq) * DE + uq * 8);
    }
    __syncthreads();

    short8 qh[2][2];   // [cb][ks]; wave owns q rows 32*wg .. 32*wg+31
    #pragma unroll
    for (int cb = 0; cb < 2; ++cb) {
        const unsigned short* src = smem + (32 * wg + 16 * cb + li) * 64;
        qh[cb][0] = *reinterpret_cast<const short8*>(src + sl0);
        qh[cb][1] = *reinterpret_cast<const short8*>(src + sl1);
    }
    __syncthreads();   // frags in regs; LDS free

    // ---- 2-deep prefetch prologue (per group): tiles kt0, kt0+1 ----
    const unsigned short* kp = Kf + (bh + rkv) * DE + ukv * 8;
    const unsigned short* vp = Vt_g + vb0 + (size_t)rkv * SEQ + ukv * 8;
    auto stageKV = [&](int slot, int tile) {
        unsigned short* base = smem + slot * 16384 + grp * 8192 + ldkv;
        gld16(base,        kp + (size_t)tile * 64 * DE);
        gld16(base + 4096, vp + (size_t)tile * 64);
    };
    stageKV(0, kt0);
    stageKV(1, kt0 + 1);

    const f32x4 zero4 = {0.f, 0.f, 0.f, 0.f};
    f32x4 accO[4][2];
    f32x4 accL[2];     // row-sum accumulator (all-ones MFMA); rescaled with accO
    #pragma unroll
    for (int vb = 0; vb < 4; ++vb) { accO[vb][0] = zero4; accO[vb][1] = zero4; }
    accL[0] = zero4; accL[1] = zero4;
    float m_c[2] = {-1e30f, -1e30f};

    short8 ones8;
    #pragma unroll
    for (int j = 0; j < 8; ++j) ones8[j] = (short)0x3C00;   // fp16 1.0

    // main loop: 16 tiles per group; ONE barrier per tile; immediate PV.
    int cs = 0;
    for (int kt = 0; kt < 16; ++kt) {
        wait_vm2();                        // this group's tile-kt K,V landed
        __builtin_amdgcn_s_barrier();
        const unsigned short* Ks = smem + cs * 16384 + grp * 8192;
        const unsigned short* Vs = Ks + 4096;

        // K fragments
        short8 kf0[4], kf1[4];
        #pragma unroll
        for (int rb = 0; rb < 4; ++rb) {
            kf0[rb] = *reinterpret_cast<const short8*>(Ks + (16 * rb + li) * 64 + sl0);
            kf1[rb] = *reinterpret_cast<const short8*>(Ks + (16 * rb + li) * 64 + sl1);
        }
        // stage next-next (dummy wrap at tail)
        int tn = kt + 2;
        if (tn >= 16) tn -= 16;
        const int ns = (cs == 0) ? 2 : cs - 1;
        stageKV(ns, kt0 + tn);

        // QK -> st (zero-C init)
        f32x4 st[4][2];
        __builtin_amdgcn_s_setprio(1);
        #pragma unroll
        for (int rb = 0; rb < 4; ++rb) {
            st[rb][0] = mfmaF(kf0[rb], qh[0][0], zero4);
            st[rb][1] = mfmaF(kf0[rb], qh[1][0], zero4);
            st[rb][0] = mfmaF(kf1[rb], qh[0][1], st[rb][0]);
            st[rb][1] = mfmaF(kf1[rb], qh[1][1], st[rb][1]);
        }
        __builtin_amdgcn_s_setprio(0);

        // softmax (base-2, Q pre-scaled), defer-max fast path -> ppk
        int ppk[2][4][2];
        #pragma unroll
        for (int cb = 0; cb < 2; ++cb) {
            float t0 = fmaxf(fmaxf(st[0][cb][0], st[0][cb][1]), st[0][cb][2]);
            float t1 = fmaxf(fmaxf(st[0][cb][3], st[1][cb][0]), st[1][cb][1]);
            float t2 = fmaxf(fmaxf(st[1][cb][2], st[1][cb][3]), st[2][cb][0]);
            float t3 = fmaxf(fmaxf(st[2][cb][1], st[2][cb][2]), st[2][cb][3]);
            float t4 = fmaxf(fmaxf(st[3][cb][0], st[3][cb][1]), st[3][cb][2]);
            float mx = fmaxf(fmaxf(fmaxf(t0, t1), st[3][cb][3]),
                             fmaxf(fmaxf(t2, t3), t4));
            if (__any(mx > m_c[cb] + 8.f)) {      // rare: true rescale
                mx = fmaxf(mx, __shfl_xor(mx, 16));
                mx = fmaxf(mx, __shfl_xor(mx, 32));
                const float mn = fmaxf(m_c[cb], mx);
                const float scl = fexp2(m_c[cb] - mn);
                #pragma unroll
                for (int vb = 0; vb < 4; ++vb) accO[vb][cb] *= scl;
                accL[cb] *= scl;
                m_c[cb] = mn;
            }
            const float mn = m_c[cb];
            #pragma unroll
            for (int rb = 0; rb < 4; ++rb) {
                const float p0 = fexp2(st[rb][cb][0] - mn);
                const float p1 = fexp2(st[rb][cb][1] - mn);
                const float p2 = fexp2(st[rb][cb][2] - mn);
                const float p3 = fexp2(st[rb][cb][3] - mn);
                ppk[cb][rb][0] = pkf16(p0, p1);
                ppk[cb][rb][1] = pkf16(p2, p3);
            }
        }

        // PV (per ks to bound register liveness)
        #pragma unroll
        for (int ks = 0; ks < 2; ++ks) {
            const int slv = ks ? sl1 : sl0;
            short8 av[4];
            #pragma unroll
            for (int vb = 0; vb < 4; ++vb)
                av[vb] = *reinterpret_cast<const short8*>(Vs + (16 * vb + li) * 64 + slv);
            __builtin_amdgcn_s_setprio(1);
            #pragma unroll
            for (int cb = 0; cb < 2; ++cb) {
                union { int i[4]; short8 s; } u4;
                u4.i[0] = ppk[cb][2 * ks][0];
                u4.i[1] = ppk[cb][2 * ks][1];
                u4.i[2] = ppk[cb][2 * ks + 1][0];
                u4.i[3] = ppk[cb][2 * ks + 1][1];
                #pragma unroll
                for (int vb = 0; vb < 4; ++vb)
                    accO[vb][cb] = mfmaF(av[vb], u4.s, accO[vb][cb]);
                accL[cb] = mfmaF(ones8, u4.s, accL[cb]);
            }
            __builtin_amdgcn_s_setprio(0);
        }

        cs = (cs == 2) ? 0 : cs + 1;
    }

    // ---- merge the two groups (exact log-sum-exp blend), write output ----
    __syncthreads();   // drains vmcnt (dummy stages) + all LDS ops; slots free
    float* xbuf = (float*)smem;
    const int xi = wg * 64 + lane;        // 0..511 within group
    if (grp == 1) {
        float* p = xbuf + (size_t)xi * 37;
        #pragma unroll
        for (int vb = 0; vb < 4; ++vb)
            #pragma unroll
            for (int cb = 0; cb < 2; ++cb)
                #pragma unroll
                for (int rr = 0; rr < 4; ++rr)
                    p[vb * 8 + cb * 4 + rr] = accO[vb][cb][rr];
        p[32] = accL[0][0];
        p[33] = accL[1][0];
        p[34] = m_c[0];
        p[35] = m_c[1];
    }
    __syncthreads();
    if (grp == 0) {
        const float* p = xbuf + (size_t)xi * 37;
        #pragma unroll
        for (int cb = 0; cb < 2; ++cb) {
            const float mB = p[34 + cb];
            const float lB = p[32 + cb];
            const float m = fmaxf(m_c[cb], mB);
            const float sA = fexp2(m_c[cb] - m);
            const float sB = fexp2(mB - m);
            const float l = accL[cb][0] * sA + lB * sB;
            const float invl = 0.125f / l;
            const int s = qp * 256 + 32 * wg + 16 * cb + li;
            #pragma unroll
            for (int vb = 0; vb < 4; ++vb) {
                const float* q = p + vb * 8 + cb * 4;
                float4 o;
                o.x = (accO[vb][cb][0] * sA + q[0] * sB) * invl;
                o.y = (accO[vb][cb][1] * sA + q[1] * sB) * invl;
                o.z = (accO[vb][cb][2] * sA + q[2] * sB) * invl;
                o.w = (accO[vb][cb][3] * sA + q[3] * sB) * invl;
                const int vd = 16 * vb + 4 * g;
                *reinterpret_cast<float4*>(
                    &out[((size_t)bat * SEQ + s) * (NH * DE) + h * DE + vd]) = o;
            }
        }
    }
}

extern "C" void kernel_launch(void* const* d_in, const int* in_sizes, int n_in,
                              void* d_out, int out_size, void* d_ws, size_t ws_size,
                              hipStream_t stream)
{
    (void)in_sizes; (void)n_in; (void)out_size; (void)ws_size;
    const float* x  = (const float*)d_in[0];
    const float* Wq = (const float*)d_in[1];
    const float* bq = (const float*)d_in[2];
    const float* Wk = (const float*)d_in[3];
    const float* bk = (const float*)d_in[4];
    const float* Wv = (const float*)d_in[5];
    const float* bv = (const float*)d_in[6];
    float* out = (float*)d_out;

    // d_out scratch: Wt fp16 (6.3 MB <= 16.8 MB), dead before attn writes.
    unsigned short* Wt = (unsigned short*)d_out;

    // d_ws: [xf 8MB][Qf 8][Kf 8][Vt 8]
    const size_t per = (size_t)BATCH * NH * SEQ * DE;   // 4 Mi elems = 8 MB fp16
    unsigned short* ws = (unsigned short*)d_ws;
    unsigned short* xf = ws;
    unsigned short* Qf = ws + per;
    unsigned short* Kf = ws + 2 * per;
    unsigned short* Vt = ws + 3 * per;

    xcvt_kernel<<<2048, 256, 0, stream>>>(x, xf);
    wcvt_kernel<<<dim3(16, NH, 3), 256, 0, stream>>>(Wq, Wk, Wv, Wt);
    proj_kernel<<<768, 256, 0, stream>>>(xf, Wt, bq, bk, bv, Qf, Kf, Vt);
    attn_kernel<<<256, 1024, 0, stream>>>(Qf, Kf, Vt, out);
}